// Round 3
// baseline (142.122 us; speedup 1.0000x reference)
//
#include <hip/hip_runtime.h>

// Who2com collapses analytically:
//   final[b,:,q] is a softmax distribution (over the compacted key dim) with a
//   zero re-inserted on the diagonal -> sum_k final[b,k,q] == 1 exactly.
//   val_mat[b,k,q] = bevs[b,q]  (key-independent)
//   => feat_fuse[b,q] = bevs[b,q];  out = mean over q = (1/N) * sum_q bevs[b,q].
// So the whole net is out[b,c,h,w] = 0.2 * sum_q bevs[b,q,c,h,w].
//
// Roofline: read 40 MB + write 8 MB -> ~7.6 us at 6.3 TB/s achievable.
// Measured dur_us (~141) is dominated by harness re-poison fills of d_ws
// (268 MB @ 41 us each per rocprof) -- not kernel time.
//
// Native vector type: __builtin_nontemporal_store requires a clang vector,
// not HIP's float4 class.

typedef float v4f __attribute__((ext_vector_type(4)));

static constexpr int B_   = 32;
static constexpr int N_   = 5;
static constexpr int CHW4 = (256 * 16 * 16) / 4;   // 16384 v4f per (b,q) slice
static constexpr int PER_THREAD = 2;

__global__ __launch_bounds__(256) void who2com_mean_kernel(
    const v4f* __restrict__ bevs, v4f* __restrict__ out) {
    const int t = blockIdx.x * blockDim.x + threadIdx.x;   // [0, B_*CHW4/2)
    const int idx0 = t * PER_THREAD;                       // first output index

    // idx0 and idx0+1 share the same b (PER_THREAD divides CHW4)
    const int b = idx0 >> 14;           // / CHW4
    const int r = idx0 & (CHW4 - 1);    // % CHW4

    const v4f* base = bevs + (size_t)b * N_ * CHW4 + r;

    v4f a0 = base[0];
    v4f a1 = base[1];
#pragma unroll
    for (int q = 1; q < N_; ++q) {
        a0 += base[q * CHW4];
        a1 += base[q * CHW4 + 1];
    }
    const float inv = 1.0f / (float)N_;
    a0 *= inv;
    a1 *= inv;

    __builtin_nontemporal_store(a0, out + idx0);
    __builtin_nontemporal_store(a1, out + idx0 + 1);
}

extern "C" void kernel_launch(void* const* d_in, const int* in_sizes, int n_in,
                              void* d_out, int out_size, void* d_ws, size_t ws_size,
                              hipStream_t stream) {
    (void)in_sizes; (void)n_in; (void)d_ws; (void)ws_size; (void)out_size;
    const v4f* bevs = (const v4f*)d_in[0];   // (B, N, C, H, W) fp32
    v4f* out = (v4f*)d_out;                  // (B, C, H, W) fp32

    const int total_threads = B_ * CHW4 / PER_THREAD;   // 262144
    const int block = 256;
    const int grid = total_threads / block;             // 1024 blocks
    who2com_mean_kernel<<<grid, block, 0, stream>>>(bevs, out);
}